// Round 1
// 467.427 us; speedup vs baseline: 2.1614x; 2.1614x over previous
//
#include <hip/hip_runtime.h>
#include <cstddef>

#define S 64
#define VOL (64*64*64)      // 262144
#define CIN 32

typedef __attribute__((ext_vector_type(8))) short bf16x8;
typedef __attribute__((ext_vector_type(4))) float floatx4;

__device__ __forceinline__ unsigned short f2bf(float f) {
    union { float f; unsigned u; } v; v.f = f;
    unsigned r = v.u + 0x7fffu + ((v.u >> 16) & 1u);   // RNE
    return (unsigned short)(r >> 16);
}
__device__ __forceinline__ float bf2f(unsigned short h) {
    union { unsigned u; float f; } v; v.u = ((unsigned)h) << 16;
    return v.f;
}
__device__ __forceinline__ int iclamp(int v, int lo, int hi) {
    return v < lo ? lo : (v > hi ? hi : v);
}

// Load 4 consecutive elements as bf16 bit patterns.
__device__ __forceinline__ void load4bf(const float* p, unsigned short* o) {
    const float4 v = *(const float4*)p;
    o[0] = f2bf(v.x); o[1] = f2bf(v.y); o[2] = f2bf(v.z); o[3] = f2bf(v.w);
}
__device__ __forceinline__ void load4bf(const unsigned short* p, unsigned short* o) {
    const ushort4 v = *(const ushort4*)p;
    o[0] = v.x; o[1] = v.y; o[2] = v.z; o[3] = v.w;
}

// Weight prep: src [co][ci][27] fp32 -> dst [tap][co][ci] bf16 (co<64).
__global__ void prep_w_kernel(const float* __restrict__ w_off,
                              const float* __restrict__ w_reg,
                              unsigned short* __restrict__ wt1,
                              unsigned short* __restrict__ wt2) {
    int i = blockIdx.x * 256 + threadIdx.x;   // i = tap*2048 + co*32 + ci
    if (i >= 27 * 64 * 32) return;
    int ci = i & 31;
    int co = (i >> 5) & 63;
    int tap = i >> 11;
    wt1[i] = f2bf(w_off[(co * 32 + ci) * 27 + tap]);
    wt2[i] = f2bf(w_reg[(co * 32 + ci) * 27 + tap]);
}

// Implicit-GEMM 3x3x3 conv via MFMA 16x16x32 bf16.  v2.
//
// Block: 256 thr = 4 waves. Output tile: 64co x 256pos = (d0..d0+1) x (h0..h0+1) x w0..63.
// Wave wv: dd = wv>>1, hh = wv&1 -> owns one (d,h) row of 64 w positions (4 nt tiles).
//   => weight bytes/pos halved vs previous 32-pos/wave layout.
//
// LDS tile: [row 0..15][slot w 0..63][ci 0..31] bf16 = 65536 B exactly (2 blocks/CU).
//   row = zz*4+yy, zz = z-(d0-1) in 0..3, yy = y-(h0-1) in 0..3. NO w-pad slots:
//   the two statically-known out-of-range lanes are zero-masked after the ds_read.
// XOR chunk swizzle: logical 16B ci-chunk j of slot s is stored at chunk (j ^ ((s>>1)&3)).
//   B-frag ds_read_b128 (lane r reads slot base+r, chunk q): bank group
//   (4*(s&1) + (q ^ ((s>>1)&3))) covers all 8 groups evenly -> conflict-free.
//
// A-frag (weights): lane holds W[co = base+(lane&15)][ci = (lane>>4)*8 + j].
// B-frag (input):   lane holds X[ci = (lane>>4)*8 + j][pos = base+(lane&15)].
// C/D: col(=pos)=lane&15, row(=co)=(lane>>4)*4+reg  [measured m89/m91].
template <typename TIN, bool WRITE_BF16>
__global__ __launch_bounds__(256, 2)
void conv_mfma_kernel(const TIN* __restrict__ src,            // [B][32][VOL]
                      const unsigned short* __restrict__ wt,  // [27][64][32] bf16
                      const float* __restrict__ bias,         // used when !WRITE_BF16
                      void* __restrict__ dstv) {              // [B][64][VOL]
    __shared__ unsigned short lds[16 * 64 * 32];   // 65536 B

    const int d0 = blockIdx.x * 2;
    const int h0 = blockIdx.y * 2;
    const int b  = blockIdx.z;
    const int t  = threadIdx.x;

    const TIN* sb = src + (size_t)b * CIN * VOL;

    // ---- staging: global [ci][pos] -> LDS [row][slot w][ci], transposed in flight ----
    // thread t: 4 w slots starting at w0=(t&15)*4, channel pair c0=(t>>4)*2.
    const int w0 = (t & 15) << 2;
    const int c0 = (t >> 4) << 1;          // even, 0..30
    const int jj = c0 >> 3;                // logical 16B chunk of c0
    const int cb = (c0 & 7) << 1;          // byte offset inside chunk (b32-aligned)
    const int sw01 = (w0 >> 1) & 3;        // swizzle term for slots w0,w0+1
    const int sw23 = ((w0 >> 1) + 1) & 3;  // swizzle term for slots w0+2,w0+3

#pragma unroll
    for (int rr = 0; rr < 16; ++rr) {
        const int z = d0 - 1 + (rr >> 2);
        const int y = h0 - 1 + (rr & 3);
        unsigned pk0 = 0, pk1 = 0, pk2 = 0, pk3 = 0;
        if (((unsigned)z < 64u) && ((unsigned)y < 64u)) {
            const TIN* p0 = sb + (size_t)c0 * VOL + (z * 64 + y) * 64 + w0;
            unsigned short va[4], vb[4];
            load4bf(p0, va);          // channel c0,   w0..w0+3
            load4bf(p0 + VOL, vb);    // channel c0+1, w0..w0+3
            pk0 = (unsigned)va[0] | ((unsigned)vb[0] << 16);
            pk1 = (unsigned)va[1] | ((unsigned)vb[1] << 16);
            pk2 = (unsigned)va[2] | ((unsigned)vb[2] << 16);
            pk3 = (unsigned)va[3] | ((unsigned)vb[3] << 16);
        }
        char* rbase = (char*)lds + (rr << 12) + cb;
        *(unsigned*)(rbase + ((w0 + 0) << 6) + ((jj ^ sw01) << 4)) = pk0;
        *(unsigned*)(rbase + ((w0 + 1) << 6) + ((jj ^ sw01) << 4)) = pk1;
        *(unsigned*)(rbase + ((w0 + 2) << 6) + ((jj ^ sw23) << 4)) = pk2;
        *(unsigned*)(rbase + ((w0 + 3) << 6) + ((jj ^ sw23) << 4)) = pk3;
    }
    __syncthreads();

    // ---- compute ----
    const int lane = t & 63;
    const int wv   = t >> 6;
    const int r    = lane & 15;
    const int q    = lane >> 4;
    const int dd   = wv >> 1;     // output d = d0 + dd
    const int hh   = wv & 1;      // output h = h0 + hh

    // Precomputed per-lane swizzled byte offsets within a row, per (nt, kw).
    int P[4][3];
#pragma unroll
    for (int nt = 0; nt < 4; ++nt)
#pragma unroll
        for (int kw = 0; kw < 3; ++kw) {
            const int s  = nt * 16 + r + kw - 1;    // input w slot (may be -1 or 64)
            const int sc = s & 63;                  // wrapped; OOB lanes zero-masked below
            P[nt][kw] = (sc << 6) + ((q ^ ((sc >> 1) & 3)) << 4);
        }

    floatx4 acc[4][4];
#pragma unroll
    for (int mt = 0; mt < 4; ++mt)
#pragma unroll
        for (int nt = 0; nt < 4; ++nt)
#pragma unroll
            for (int rg = 0; rg < 4; ++rg) acc[mt][nt][rg] = 0.f;

    const bf16x8 z8 = {0, 0, 0, 0, 0, 0, 0, 0};

#pragma unroll
    for (int tap = 0; tap < 27; ++tap) {
        const int kd = tap / 9;
        const int kh = (tap % 9) / 3;
        const int kw = tap % 3;
        const int rowb = ((((dd + kd) << 2) + hh + kh) << 12);   // row * 4096 B

        bf16x8 afr[4];
#pragma unroll
        for (int mt = 0; mt < 4; ++mt)
            afr[mt] = *(const bf16x8*)&wt[tap * 2048 + (mt * 16 + r) * 32 + q * 8];

        bf16x8 bfr[4];
#pragma unroll
        for (int nt = 0; nt < 4; ++nt)
            bfr[nt] = *(const bf16x8*)((const char*)lds + rowb + P[nt][kw]);

        // zero-mask the two statically-OOB lanes (w_in = -1 and w_in = 64)
        if (kw == 0) { if (r == 0)  bfr[0] = z8; }
        if (kw == 2) { if (r == 15) bfr[3] = z8; }

#pragma unroll
        for (int mt = 0; mt < 4; ++mt)
#pragma unroll
            for (int nt = 0; nt < 4; ++nt)
                acc[mt][nt] = __builtin_amdgcn_mfma_f32_16x16x32_bf16(
                                  afr[mt], bfr[nt], acc[mt][nt], 0, 0, 0);
    }

    // ---- epilogue ----
    const int dw = (d0 + dd) * 4096 + (h0 + hh) * 64;
#pragma unroll
    for (int mt = 0; mt < 4; ++mt) {
#pragma unroll
        for (int nt = 0; nt < 4; ++nt) {
#pragma unroll
            for (int rg = 0; rg < 4; ++rg) {
                const int co  = mt * 16 + q * 4 + rg;
                const int pos = dw + nt * 16 + r;
                const size_t oidx = ((size_t)(b * 64 + co)) * VOL + pos;
                const float v = acc[mt][nt][rg];
                if (WRITE_BF16) {
                    ((unsigned short*)dstv)[oidx] = f2bf(v);
                } else {
                    ((float*)dstv)[oidx] = v + bias[co];
                }
            }
        }
    }
}

// Trilinear gather. Tile: (b, c, h) fixed; 16 d x 16 w. Lanes d-fastest for
// coalesced x reads (sample coords: ix~d is the contiguous axis); LDS 16x16
// transpose so sampled writes are w-coalesced.
__global__ __launch_bounds__(256)
void gather_kernel(const float* __restrict__ x,
                   const unsigned short* __restrict__ off,   // [B][64][VOL] bf16
                   unsigned short* __restrict__ sampled) {   // [B][32][VOL] bf16
    __shared__ float res[16][17];

    const int bx = blockIdx.x;          // wt4 + 4*dt + 16*h
    const int wt4 = bx & 3;
    const int dt  = (bx >> 2) & 3;
    const int h   = bx >> 4;
    const int c = blockIdx.y;
    const int b = blockIdx.z;
    const int t = threadIdx.x;
    const int d_i = t & 15;
    const int w_i = t >> 4;
    const int d = dt * 16 + d_i;
    const int w = wt4 * 16 + w_i;
    const int p = d * 4096 + h * 64 + w;

    const float* vol = x + ((size_t)(b * CIN + c)) * VOL;
    const float offw = bf2f(off[((size_t)(b * 64 + c)) * VOL + p]);
    const float offh = bf2f(off[((size_t)(b * 64 + 32 + c)) * VOL + p]);

    // Faithful-bug mapping: ix = off_h*31.5 + d, iy = off_w*31.5 + h, iz = off_h*31.5 + w
    const float ix = offh * 31.5f + (float)d;
    const float iy = offw * 31.5f + (float)h;
    const float iz = offh * 31.5f + (float)w;

    const float x0f = floorf(ix), y0f = floorf(iy), z0f = floorf(iz);
    const float tx = ix - x0f, ty = iy - y0f, tz = iz - z0f;
    const int ix0 = (int)x0f, iy0 = (int)y0f, iz0 = (int)z0f;

    float out = 0.f;
#pragma unroll
    for (int dz = 0; dz < 2; ++dz) {
#pragma unroll
        for (int dy = 0; dy < 2; ++dy) {
#pragma unroll
            for (int dx = 0; dx < 2; ++dx) {
                const int xc = ix0 + dx, yc = iy0 + dy, zc = iz0 + dz;
                const bool inb = ((unsigned)xc < 64u) && ((unsigned)yc < 64u)
                              && ((unsigned)zc < 64u);
                const float wgt = (dx ? tx : 1.f - tx)
                                * (dy ? ty : 1.f - ty)
                                * (dz ? tz : 1.f - tz);
                const int xcc = iclamp(xc, 0, 63);
                const int ycc = iclamp(yc, 0, 63);
                const int zcc = iclamp(zc, 0, 63);
                const float val = vol[(zcc * 64 + ycc) * 64 + xcc];
                out += inb ? wgt * val : 0.f;
            }
        }
    }

    res[w_i][d_i] = out;
    __syncthreads();

    const int w_o = t & 15;
    const int d_o = t >> 4;
    sampled[((size_t)(b * CIN + c)) * VOL + (dt * 16 + d_o) * 4096 + h * 64
            + wt4 * 16 + w_o] = f2bf(res[w_o][d_o]);
}

extern "C" void kernel_launch(void* const* d_in, const int* in_sizes, int n_in,
                              void* d_out, int out_size, void* d_ws, size_t ws_size,
                              hipStream_t stream) {
    (void)in_sizes; (void)n_in; (void)out_size; (void)ws_size;
    const float* x     = (const float*)d_in[0];   // (2,32,64,64,64)
    const float* w_off = (const float*)d_in[1];   // (96,32,3,3,3)
    const float* w_reg = (const float*)d_in[2];   // (64,32,3,3,3)
    const float* b_reg = (const float*)d_in[3];   // (64,)
    float* out = (float*)d_out;                   // (2,64,64,64,64)

    // ws: offsets bf16 (64 MiB) | sampled bf16 (32 MiB) | wt1 | wt2
    unsigned short* off     = (unsigned short*)d_ws;
    unsigned short* sampled = off + (size_t)2 * 64 * VOL;
    unsigned short* wt1     = sampled + (size_t)2 * CIN * VOL;
    unsigned short* wt2     = wt1 + 27 * 64 * 32;

    prep_w_kernel<<<216, 256, 0, stream>>>(w_off, w_reg, wt1, wt2);

    dim3 cgrid(32, 32, 2);
    conv_mfma_kernel<float, true><<<cgrid, 256, 0, stream>>>(x, wt1, nullptr, (void*)off);

    dim3 ggrid(1024, 32, 2);
    gather_kernel<<<ggrid, 256, 0, stream>>>(x, off, sampled);

    conv_mfma_kernel<unsigned short, false><<<cgrid, 256, 0, stream>>>(sampled, wt2, b_reg, (void*)out);
}

// Round 2
// 426.198 us; speedup vs baseline: 2.3705x; 1.0967x over previous
//
#include <hip/hip_runtime.h>
#include <cstddef>

#define S 64
#define VOL (64*64*64)      // 262144
#define CIN 32

typedef __attribute__((ext_vector_type(8))) short bf16x8;
typedef __attribute__((ext_vector_type(4))) float floatx4;

struct __attribute__((packed, aligned(4))) fpair { float x, y; };

__device__ __forceinline__ unsigned short f2bf(float f) {
    union { float f; unsigned u; } v; v.f = f;
    unsigned r = v.u + 0x7fffu + ((v.u >> 16) & 1u);   // RNE
    return (unsigned short)(r >> 16);
}
__device__ __forceinline__ float bf2f(unsigned short h) {
    union { unsigned u; float f; } v; v.u = ((unsigned)h) << 16;
    return v.f;
}
__device__ __forceinline__ int iclamp(int v, int lo, int hi) {
    return v < lo ? lo : (v > hi ? hi : v);
}

// Load 4 consecutive elements as bf16 bit patterns.
__device__ __forceinline__ void load4bf(const float* p, unsigned short* o) {
    const float4 v = *(const float4*)p;
    o[0] = f2bf(v.x); o[1] = f2bf(v.y); o[2] = f2bf(v.z); o[3] = f2bf(v.w);
}
__device__ __forceinline__ void load4bf(const unsigned short* p, unsigned short* o) {
    const ushort4 v = *(const ushort4*)p;
    o[0] = v.x; o[1] = v.y; o[2] = v.z; o[3] = v.w;
}

// Weight prep: src [co][ci][27] fp32 -> dst [tap][co][ci] bf16 (co<64).
__global__ void prep_w_kernel(const float* __restrict__ w_off,
                              const float* __restrict__ w_reg,
                              unsigned short* __restrict__ wt1,
                              unsigned short* __restrict__ wt2) {
    int i = blockIdx.x * 256 + threadIdx.x;   // i = tap*2048 + co*32 + ci
    if (i >= 27 * 64 * 32) return;
    int ci = i & 31;
    int co = (i >> 5) & 63;
    int tap = i >> 11;
    wt1[i] = f2bf(w_off[(co * 32 + ci) * 27 + tap]);
    wt2[i] = f2bf(w_reg[(co * 32 + ci) * 27 + tap]);
}

// Implicit-GEMM 3x3x3 conv via MFMA 16x16x32 bf16.  v2.
//
// Block: 256 thr = 4 waves. Output tile: 64co x 256pos = (d0..d0+1) x (h0..h0+1) x w0..63.
// Wave wv: dd = wv>>1, hh = wv&1 -> owns one (d,h) row of 64 w positions (4 nt tiles).
//
// LDS tile: [row 0..15][slot w 0..63][ci 0..31] bf16 = 65536 B exactly (2 blocks/CU).
// XOR chunk swizzle: logical 16B ci-chunk j of slot s stored at chunk (j ^ ((s>>1)&3)).
//
// A-frag (weights): lane holds W[co = base+(lane&15)][ci = (lane>>4)*8 + j].
// B-frag (input):   lane holds X[ci = (lane>>4)*8 + j][pos = base+(lane&15)].
// C/D: col(=pos)=lane&15, row(=co)=(lane>>4)*4+reg  [measured m89/m91].
//
// WRITE_OFF epilogue: pack (off_w = co c, off_h = co c+32) as one u32 per pos,
// layout [B][32][VOL] (lo = offw bf16 bits, hi = offh bf16 bits).
template <typename TIN, bool WRITE_OFF>
__global__ __launch_bounds__(256, 2)
void conv_mfma_kernel(const TIN* __restrict__ src,            // [B][32][VOL]
                      const unsigned short* __restrict__ wt,  // [27][64][32] bf16
                      const float* __restrict__ bias,         // used when !WRITE_OFF
                      void* __restrict__ dstv) {
    __shared__ unsigned short lds[16 * 64 * 32];   // 65536 B

    const int d0 = blockIdx.x * 2;
    const int h0 = blockIdx.y * 2;
    const int b  = blockIdx.z;
    const int t  = threadIdx.x;

    const TIN* sb = src + (size_t)b * CIN * VOL;

    // ---- staging: global [ci][pos] -> LDS [row][slot w][ci], transposed in flight ----
    const int w0 = (t & 15) << 2;
    const int c0 = (t >> 4) << 1;          // even, 0..30
    const int jj = c0 >> 3;                // logical 16B chunk of c0
    const int cb = (c0 & 7) << 1;          // byte offset inside chunk (b32-aligned)
    const int sw01 = (w0 >> 1) & 3;        // swizzle term for slots w0,w0+1
    const int sw23 = ((w0 >> 1) + 1) & 3;  // swizzle term for slots w0+2,w0+3

#pragma unroll
    for (int rr = 0; rr < 16; ++rr) {
        const int z = d0 - 1 + (rr >> 2);
        const int y = h0 - 1 + (rr & 3);
        unsigned pk0 = 0, pk1 = 0, pk2 = 0, pk3 = 0;
        if (((unsigned)z < 64u) && ((unsigned)y < 64u)) {
            const TIN* p0 = sb + (size_t)c0 * VOL + (z * 64 + y) * 64 + w0;
            unsigned short va[4], vb[4];
            load4bf(p0, va);          // channel c0,   w0..w0+3
            load4bf(p0 + VOL, vb);    // channel c0+1, w0..w0+3
            pk0 = (unsigned)va[0] | ((unsigned)vb[0] << 16);
            pk1 = (unsigned)va[1] | ((unsigned)vb[1] << 16);
            pk2 = (unsigned)va[2] | ((unsigned)vb[2] << 16);
            pk3 = (unsigned)va[3] | ((unsigned)vb[3] << 16);
        }
        char* rbase = (char*)lds + (rr << 12) + cb;
        *(unsigned*)(rbase + ((w0 + 0) << 6) + ((jj ^ sw01) << 4)) = pk0;
        *(unsigned*)(rbase + ((w0 + 1) << 6) + ((jj ^ sw01) << 4)) = pk1;
        *(unsigned*)(rbase + ((w0 + 2) << 6) + ((jj ^ sw23) << 4)) = pk2;
        *(unsigned*)(rbase + ((w0 + 3) << 6) + ((jj ^ sw23) << 4)) = pk3;
    }
    __syncthreads();

    // ---- compute ----
    const int lane = t & 63;
    const int wv   = t >> 6;
    const int r    = lane & 15;
    const int q    = lane >> 4;
    const int dd   = wv >> 1;     // output d = d0 + dd
    const int hh   = wv & 1;      // output h = h0 + hh

    int P[4][3];
#pragma unroll
    for (int nt = 0; nt < 4; ++nt)
#pragma unroll
        for (int kw = 0; kw < 3; ++kw) {
            const int s  = nt * 16 + r + kw - 1;
            const int sc = s & 63;
            P[nt][kw] = (sc << 6) + ((q ^ ((sc >> 1) & 3)) << 4);
        }

    floatx4 acc[4][4];
#pragma unroll
    for (int mt = 0; mt < 4; ++mt)
#pragma unroll
        for (int nt = 0; nt < 4; ++nt)
#pragma unroll
            for (int rg = 0; rg < 4; ++rg) acc[mt][nt][rg] = 0.f;

    const bf16x8 z8 = {0, 0, 0, 0, 0, 0, 0, 0};

#pragma unroll
    for (int tap = 0; tap < 27; ++tap) {
        const int kd = tap / 9;
        const int kh = (tap % 9) / 3;
        const int kw = tap % 3;
        const int rowb = ((((dd + kd) << 2) + hh + kh) << 12);   // row * 4096 B

        bf16x8 afr[4];
#pragma unroll
        for (int mt = 0; mt < 4; ++mt)
            afr[mt] = *(const bf16x8*)&wt[tap * 2048 + (mt * 16 + r) * 32 + q * 8];

        bf16x8 bfr[4];
#pragma unroll
        for (int nt = 0; nt < 4; ++nt)
            bfr[nt] = *(const bf16x8*)((const char*)lds + rowb + P[nt][kw]);

        if (kw == 0) { if (r == 0)  bfr[0] = z8; }
        if (kw == 2) { if (r == 15) bfr[3] = z8; }

#pragma unroll
        for (int mt = 0; mt < 4; ++mt)
#pragma unroll
            for (int nt = 0; nt < 4; ++nt)
                acc[mt][nt] = __builtin_amdgcn_mfma_f32_16x16x32_bf16(
                                  afr[mt], bfr[nt], acc[mt][nt], 0, 0, 0);
    }

    // ---- epilogue ----
    const int dw = (d0 + dd) * 4096 + (h0 + hh) * 64;
    if (WRITE_OFF) {
#pragma unroll
        for (int mt = 0; mt < 2; ++mt) {
#pragma unroll
            for (int nt = 0; nt < 4; ++nt) {
#pragma unroll
                for (int rg = 0; rg < 4; ++rg) {
                    const int c   = mt * 16 + q * 4 + rg;       // 0..31
                    const int pos = dw + nt * 16 + r;
                    const unsigned pk = (unsigned)f2bf(acc[mt][nt][rg])
                                      | ((unsigned)f2bf(acc[mt + 2][nt][rg]) << 16);
                    ((unsigned*)dstv)[((size_t)(b * 32 + c)) * VOL + pos] = pk;
                }
            }
        }
    } else {
#pragma unroll
        for (int mt = 0; mt < 4; ++mt) {
#pragma unroll
            for (int nt = 0; nt < 4; ++nt) {
#pragma unroll
                for (int rg = 0; rg < 4; ++rg) {
                    const int co  = mt * 16 + q * 4 + rg;
                    const int pos = dw + nt * 16 + r;
                    ((float*)dstv)[((size_t)(b * 64 + co)) * VOL + pos]
                        = acc[mt][nt][rg] + bias[co];
                }
            }
        }
    }
}

// Trilinear gather, v2.
//  - offsets packed u32 [B][32][VOL] (lo=offw, hi=offh), loaded COALESCED
//    (w-fastest lanes) and transposed through LDS to the d-fastest compute order.
//  - dx taps paired into one align(4) float-pair load per (dz,dy).
//  - XCD-affinity remap: all 1024 blocks of one (b,c) volume land on one XCD
//    (gid%8 heuristic) so its 1 MiB x-volume stays L2-resident.
__global__ __launch_bounds__(256)
void gather_kernel(const float* __restrict__ x,
                   const unsigned* __restrict__ off32,       // [B][32][VOL]
                   unsigned short* __restrict__ sampled) {   // [B][32][VOL] bf16
    __shared__ unsigned ostage[16][17];
    __shared__ float res[16][17];

    const unsigned gid = blockIdx.x;        // 0..65535
    const int xcd = gid & 7;
    const int j   = gid >> 3;               // 0..8191
    const int v   = xcd + ((j >> 10) << 3); // volume id 0..63, fixed XCD per volume
    const int bx  = j & 1023;
    const int c   = v & 31;
    const int b   = v >> 5;
    const int wt4 = bx & 3;
    const int dt  = (bx >> 2) & 3;
    const int h   = bx >> 4;
    const int t   = threadIdx.x;

    // coalesced offset stage: lane w-fastest -> one 64B line per 16-lane group
    {
        const int wA = t & 15, dA = t >> 4;
        ostage[dA][wA] = off32[((size_t)(b * 32 + c)) * VOL
                               + (dt * 16 + dA) * 4096 + h * 64 + wt4 * 16 + wA];
    }
    __syncthreads();

    const int d_i = t & 15;
    const int w_i = t >> 4;
    const int d = dt * 16 + d_i;
    const int w = wt4 * 16 + w_i;

    const unsigned ow = ostage[d_i][w_i];
    const float offw = bf2f((unsigned short)(ow & 0xffffu));
    const float offh = bf2f((unsigned short)(ow >> 16));

    const float* vol = x + ((size_t)(b * CIN + c)) * VOL;

    // Faithful-bug mapping: ix = off_h*31.5 + d, iy = off_w*31.5 + h, iz = off_h*31.5 + w
    const float ix = offh * 31.5f + (float)d;
    const float iy = offw * 31.5f + (float)h;
    const float iz = offh * 31.5f + (float)w;

    const float x0f = floorf(ix), y0f = floorf(iy), z0f = floorf(iz);
    const float tx = ix - x0f, ty = iy - y0f, tz = iz - z0f;
    const int ix0 = (int)x0f, iy0 = (int)y0f, iz0 = (int)z0f;

    // paired x taps: one float-pair load at bx0, select handles the clamp edge
    const int bx0 = iclamp(ix0, 0, 62);
    const bool sel = (ix0 == bx0);                    // ix0 in [0,62]
    const float w0x = ((unsigned)ix0 < 64u)       ? (1.f - tx) : 0.f;
    const float w1x = ((unsigned)(ix0 + 1) < 64u) ? tx         : 0.f;

    float out = 0.f;
#pragma unroll
    for (int dz = 0; dz < 2; ++dz) {
        const int zc = iz0 + dz;
        const bool zok = ((unsigned)zc < 64u);
        const int zcc = iclamp(zc, 0, 63);
        const float wz = dz ? tz : 1.f - tz;
#pragma unroll
        for (int dy = 0; dy < 2; ++dy) {
            const int yc = iy0 + dy;
            const bool yok = ((unsigned)yc < 64u);
            const int ycc = iclamp(yc, 0, 63);
            const float wzy = (zok && yok) ? wz * (dy ? ty : 1.f - ty) : 0.f;

            const fpair vp = *(const fpair*)&vol[(zcc * 64 + ycc) * 64 + bx0];
            const float v0 = sel ? vp.x : vp.y;
            const float v1 = sel ? vp.y : vp.x;
            out += wzy * (w0x * v0 + w1x * v1);
        }
    }

    res[w_i][d_i] = out;
    __syncthreads();

    const int w_o = t & 15;
    const int d_o = t >> 4;
    sampled[((size_t)(b * CIN + c)) * VOL + (dt * 16 + d_o) * 4096 + h * 64
            + wt4 * 16 + w_o] = f2bf(res[w_o][d_o]);
}

extern "C" void kernel_launch(void* const* d_in, const int* in_sizes, int n_in,
                              void* d_out, int out_size, void* d_ws, size_t ws_size,
                              hipStream_t stream) {
    (void)in_sizes; (void)n_in; (void)out_size; (void)ws_size;
    const float* x     = (const float*)d_in[0];   // (2,32,64,64,64)
    const float* w_off = (const float*)d_in[1];   // (96,32,3,3,3)
    const float* w_reg = (const float*)d_in[2];   // (64,32,3,3,3)
    const float* b_reg = (const float*)d_in[3];   // (64,)
    float* out = (float*)d_out;                   // (2,64,64,64,64)

    // ws: packed offsets u32 (64 MiB) | sampled bf16 (32 MiB) | wt1 | wt2
    unsigned* off32         = (unsigned*)d_ws;
    unsigned short* sampled = (unsigned short*)(off32 + (size_t)2 * 32 * VOL);
    unsigned short* wt1     = sampled + (size_t)2 * CIN * VOL;
    unsigned short* wt2     = wt1 + 27 * 64 * 32;

    prep_w_kernel<<<216, 256, 0, stream>>>(w_off, w_reg, wt1, wt2);

    dim3 cgrid(32, 32, 2);
    conv_mfma_kernel<float, true><<<cgrid, 256, 0, stream>>>(x, wt1, nullptr, (void*)off32);

    gather_kernel<<<65536, 256, 0, stream>>>(x, off32, sampled);

    conv_mfma_kernel<unsigned short, false><<<cgrid, 256, 0, stream>>>(sampled, wt2, b_reg, (void*)out);
}